// Round 5
// baseline (252.553 us; speedup 1.0000x reference)
//
#include <hip/hip_runtime.h>

// EWMA scan z_t = lam*z_{t-1} + (1-lam)*x_t over [B,L,K], chunk-parallel with
// 128-step warm-up (error <= lam^129 * max|z| ~ 1e-3 << 1.7e-2 threshold).
//
// R4 FAILED: CHUNK 128->32: occupancy 9->33% but FETCH 130->300 MB -> 130us.
// R5 NEUTRAL: K-split 4 (16 waves/CU, 1x traffic) -> 95us, 2.8 TB/s.
// R6 NEUTRAL: 4-stage VGPR pipeline -> compiler collapses VGPR pipelines.
// R7 NEUTRAL: LDS-DMA ring, 32 loads/wave in flight BY CONSTRUCTION
//     (128 KB/CU posted) -> still 2.73 TB/s. Depth theory REFUTED: Little's
//     law gives 43 B/cy/CU from posted depth vs 4.5 observed -> the cap is
//     a SERVICE rate. Common factor across all flat rounds, never ablated:
//     __builtin_nontemporal_store. The 6.3 TB/s copy ubench (same 1:1
//     read:write mix) uses plain stores; R4 broke the band only by diluting
//     the nt-write fraction with extra reads.
// R8: single-variable ablation of R7 -> plain stores. Theory: nt streams
//     past L2 with per-request DRAM commits (frequent read/write bus
//     turnarounds); plain stores coalesce dirty lines in L2/L3 and write
//     back in batched bursts. Stores are full 256B wave-contiguous lines ->
//     no RFO amplification expected (watch FETCH_SIZE to confirm).

#define LAM    0.95f
#define CHUNK  128
#define WARM   128
#define TSTEPS 16

constexpr int B = 16;
constexpr int L = 8192;
constexpr int K = 256;
constexpr int G = L / CHUNK;    // 64 chunks per batch

typedef const __attribute__((address_space(1))) unsigned int gu32;
typedef __attribute__((address_space(3)))       unsigned int lu32;

#define WAITV(N)                                                   \
    do {                                                           \
        asm volatile("s_waitcnt vmcnt(" #N ")" ::: "memory");      \
        __builtin_amdgcn_sched_barrier(0);                         \
    } while (0)

__global__ __launch_bounds__(256) void ewma_kernel(const float* __restrict__ x,
                                                   float* __restrict__ out) {
    __shared__ float lds[4][2][TSTEPS][64];       // 32 KB: [wave][slot][step][lane]

    const int wib  = (int)(threadIdx.x >> 6);     // K-slice 0..3 within block
    const int lane = threadIdx.x & 63;
    const int j    = blockIdx.x & (G - 1);        // chunk index
    const int b    = blockIdx.x >> 6;             // batch
    const int s    = j * CHUNK;                   // stored-region start
    const int t0   = (j == 0) ? 0 : (s - WARM);   // scan start (warm-up)

    const long chan = (long)b * L * K + wib * 64 + lane;  // this lane's channel
    const float* __restrict__ pin  = x   + chan + (long)t0 * K;
    float*       __restrict__ pout = out + chan + (long)t0 * K;

    const float c = 1.0f - LAM;
    float z = 0.f;

    const int total      = (s + CHUNK) - t0;      // 128 (chunk 0) or 256
    const int NT         = total / TSTEPS;        // 8 or 16 tiles
    const int warm_tiles = (s - t0) / TSTEPS;     // 0 or 8

    // Issue one tile's worth of fire-and-forget DMA loads (16 x 256B).
    auto stage = [&](int tile) {
        const float* p = pin + (long)tile * TSTEPS * K;
        lu32* lp = (lu32*)&lds[wib][tile & 1][0][0];   // wave-uniform base
        #pragma unroll
        for (int u = 0; u < TSTEPS; ++u)
            __builtin_amdgcn_global_load_lds((gu32*)(p + (long)u * K),
                                             lp + (long)u * 64, 4, 0, 0);
    };

    // Consume a tile from its LDS slot: 16 serial fma steps (+ plain stores).
    auto consume = [&](int tile) {
        const bool st = (tile >= warm_tiles);     // wave-uniform
        float* p = pout + (long)tile * TSTEPS * K;
        #pragma unroll
        for (int u = 0; u < TSTEPS; ++u) {
            const float xv = lds[wib][tile & 1][u][lane];
            z = fmaf(LAM, z, c * xv);
            if (st) p[(long)u * K] = z;           // PLAIN store (R8 ablation)
        }
    };

    stage(0);
    stage(1);

    // Segment 1: younger ops at wait = 16 loads only (tiles < warm_tiles
    // don't store). Covers i=0..warm_tiles (first stored tile's previous
    // tile is warm -> no stores among the youngest 16..32 either).
    const int W1 = warm_tiles + 1;
    int i = 0;
    for (; i < W1; ++i) {
        WAITV(16);
        consume(i);
        if (i + 2 < NT) stage(i + 2);
    }
    // Segment 2 (steady state): younger = 16 loads(i+1) + 16 stores(i-1).
    for (; i < NT - 1; ++i) {
        WAITV(32);
        consume(i);
        if (i + 2 < NT) stage(i + 2);
    }
    // Last tile: younger = 16 stores(NT-2) only (no loads after tile NT-1).
    WAITV(16);
    consume(NT - 1);
}

extern "C" void kernel_launch(void* const* d_in, const int* in_sizes, int n_in,
                              void* d_out, int out_size, void* d_ws, size_t ws_size,
                              hipStream_t stream) {
    const float* x = (const float*)d_in[0];
    float* out = (float*)d_out;

    const int blocks = B * G;            // 1024 blocks (one per (b,chunk))
    hipLaunchKernelGGL(ewma_kernel, dim3(blocks), dim3(256), 0, stream, x, out);
}